// Round 2
// baseline (302.990 us; speedup 1.0000x reference)
//
#include <hip/hip_runtime.h>
#include <cstdint>

// Problem constants (from reference)
#define BB 32
#define TV 8192
#define KK 64
#define TS 128
#define MARGIN_F 0.1f
#define LAMBDA_F 0.5f

#define TT 128                                 // t-tile per block (was 256)
static constexpr int KSTR = BB * TV;           // pred_intervened stride per k
static constexpr int NTILE = TV / TT;          // 64 tiles per batch

// Workspace (floats, contiguous so one memset covers):
//   gsa[KK*BB] : sum(eff*aligned) per (k,b)
//   gsv[KK*BB] : sum(eff*valid)   per (k,b)
//   gca[KK*BB] : count(aligned)   per (k,b)
//   len[BB]    : count(valid)     per b (int)
// en = (gsv-gsa)/(len-gca).
//
// R4 rewrite rationale (counters: VALUBusy 12.8, HBM 11.6%, Occ 28.5 -> pure
// latency/imbalance bound at 930 GB/s demand rate):
//  * TT 256->128: 2048 blocks (8/CU of work vs ~4-5 resident) -> backfill
//    rebalances the 25% invalid-tile tail; XOR swizzle decorrelates CU<->tile.
//  * LDS 36.4KB -> ~3KB: epilogue slabs replaced by 64-lane shuffle reduce
//    (each wave owns k exclusively -> no cross-wave combine needed).
//  * MLP: Phase A batches 8 int4 loads before ballots; Phase B issues all 16
//    strided float2 loads up front (8KB/wave in flight vs ~1KB before).
// R5: identical source — R4 bench was an infra failure (container acquisition),
// not a kernel verdict; re-running to get the measurement.
__global__ __launch_bounds__(256, 4) void fused_kernel(
    const float* __restrict__ po, const float* __restrict__ pi,
    const int* __restrict__ idx, const int* __restrict__ gt,
    const int* __restrict__ mv,
    float* __restrict__ gsa, float* __restrict__ gsv,
    float* __restrict__ gca, int* __restrict__ len) {
  const int tid = threadIdx.x;
  const int lane = tid & 63;
  const int w = tid >> 6;

  const int bid = blockIdx.x;
  const int b = bid >> 6;                      // 0..31
  const int tile = (bid & 63) ^ b;             // bijective per b; decorrelates
  const int t0 = tile * TT;                    // CU <-> tile under strided dispatch

  __shared__ unsigned long long ph[4][65];     // wave w's 32-row half-plane per k
  __shared__ unsigned sV[4];                   // valid bits, rows [32w,32w+32)
  __shared__ float so[TT];                     // sigmoid(pred_orig) tile

  // ---- Phase A ----  wave w owns rows [t0+32w, t0+32w+32)
  const int rbase = b * TV + t0 + 32 * w;
  const int mvv = (lane < 32) ? mv[rbase + lane] : 0;
  const unsigned V32 = (unsigned)__ballot(mvv != 0);
  if (lane == 0) {
    sV[w] = V32;
    if (V32) atomicAdd(&len[b], __popc(V32));
  }
  if (tid < TT) so[tid] = __fdividef(1.f, 1.f + __expf(-po[b * TV + t0 + tid]));

  const int c = idx[lane];                     // lane extracts column for k=lane
  const int csel = c & 3, csh = c >> 2;
  const int h32 = (w & 1) * 32;                // bit offset of this wave's half
  unsigned long long plane = 0ull;
  if (V32 != 0u) {
    const int4* rowp = (const int4*)(gt + (size_t)rbase * TS);
#pragma unroll
    for (int batch = 0; batch < 2; ++batch) {
      int4 v[8];                               // 8 loads in flight, then ballots
#pragma unroll
      for (int i = 0; i < 8; ++i) v[i] = rowp[(batch * 8 + i) * 64 + lane];
#pragma unroll
      for (int i = 0; i < 8; ++i) {
        const int it = batch * 8 + i;          // covers rows 2*it, 2*it+1
        const unsigned long long b0 = __ballot(v[i].x > 0);
        const unsigned long long b1 = __ballot(v[i].y > 0);
        const unsigned long long b2 = __ballot(v[i].z > 0);
        const unsigned long long b3 = __ballot(v[i].w > 0);
        const unsigned long long sel =
            (csel == 0) ? b0 : (csel == 1) ? b1 : (csel == 2) ? b2 : b3;
        plane |= ((sel >> csh) & 1ull) << (h32 + 2 * it);
        plane |= ((sel >> (32 + csh)) & 1ull) << (h32 + 2 * it + 1);
      }
    }
    plane &= ((unsigned long long)V32) << h32; // aligned requires valid
  }
  ph[w][lane] = plane;
  __syncthreads();

  // fully-invalid tile: nothing to add
  if ((sV[0] | sV[1] | sV[2] | sV[3]) == 0u) return;

  // ---- Phase B ----  lane handles t_local = 2*lane, 2*lane+1
  const int bitpos = (lane & 31) * 2;
  const unsigned long long Vlo =
      (unsigned long long)sV[0] | ((unsigned long long)sV[1] << 32);
  const unsigned long long Vhi =
      (unsigned long long)sV[2] | ((unsigned long long)sV[3] << 32);
  const unsigned long long myV = (lane < 32) ? Vlo : Vhi;
  const unsigned vb2 = (unsigned)((myV >> bitpos) & 3ull);
  const float2 so2 = *(const float2*)&so[2 * lane];
  const float* pib = pi + (size_t)b * TV + t0 + 2 * lane;
  const int kbase = w * 16;                    // this wave's exclusive k range

  float2 x[16];                                // all 16 strided loads in flight
#pragma unroll
  for (int i = 0; i < 16; ++i) {
    x[i] = make_float2(0.f, 0.f);
    if (vb2) x[i] = *(const float2*)(pib + (size_t)(kbase + i) * KSTR);
  }

  float sa[16], sv[16];
#pragma unroll
  for (int i = 0; i < 16; ++i) {
    const int k = kbase + i;
    const unsigned long long mine =
        (lane < 32) ? (ph[0][k] | ph[1][k]) : (ph[2][k] | ph[3][k]);
    const unsigned ab2 = (unsigned)((mine >> bitpos) & 3ull);
    const float e0 = fabsf(so2.x - __fdividef(1.f, 1.f + __expf(-x[i].x)));
    const float e1 = fabsf(so2.y - __fdividef(1.f, 1.f + __expf(-x[i].y)));
    float a = 0.f, vv = 0.f;
    if (vb2 & 1u) vv += e0;
    if (vb2 & 2u) vv += e1;
    if (ab2 & 1u) a += e0;
    if (ab2 & 2u) a += e1;
    sa[i] = a;
    sv[i] = vv;
  }

  // per-k 64-lane shuffle reduce; each (k,b) pair hit by one wave per tile
#pragma unroll
  for (int i = 0; i < 16; ++i) {
    float A = sa[i], Vv = sv[i];
#pragma unroll
    for (int off = 32; off; off >>= 1) {
      A += __shfl_xor(A, off);
      Vv += __shfl_xor(Vv, off);
    }
    if (lane == 0) {
      const int k = kbase + i;
      if (A != 0.f) atomicAdd(&gsa[k * BB + b], A);
      if (Vv != 0.f) atomicAdd(&gsv[k * BB + b], Vv);
      const int ca =
          __popcll(ph[0][k] | ph[1][k]) + __popcll(ph[2][k] | ph[3][k]);
      if (ca) atomicAdd(&gca[k * BB + b], (float)ca);
    }
  }
}

// ---------------------------------------------------------------------------
// Finalize: 1 block over the 2048 (k,b) pairs (logic verified in R2/R3).
// ---------------------------------------------------------------------------
__global__ __launch_bounds__(256) void fin_kernel(
    const float* __restrict__ gsa, const float* __restrict__ gsv,
    const float* __restrict__ gca, const int* __restrict__ len,
    float* __restrict__ out) {
  float s = 0.f;
  for (int i = threadIdx.x; i < KK * BB; i += 256) {
    const int b = i & (BB - 1);
    const float ca = gca[i];
    const float cn = (float)len[b] - ca;
    if (ca > 0.f && cn > 0.f) {
      const float sa = gsa[i];
      const float sv = gsv[i];
      const float d = MARGIN_F - (sa / ca - (sv - sa) / cn);
      s += d > 0.f ? d : 0.f;
    }
  }
#pragma unroll
  for (int off = 32; off > 0; off >>= 1) s += __shfl_down(s, off);
  __shared__ float ws4[4];
  if ((threadIdx.x & 63) == 0) ws4[threadIdx.x >> 6] = s;
  __syncthreads();
  if (threadIdx.x == 0) {
    const float S = ws4[0] + ws4[1] + ws4[2] + ws4[3];
    const float ac = S * (1.0f / (float)(KK * BB));
    out[0] = ac;
    out[1] = ac * LAMBDA_F;
  }
}

extern "C" void kernel_launch(void* const* d_in, const int* in_sizes, int n_in,
                              void* d_out, int out_size, void* d_ws, size_t ws_size,
                              hipStream_t stream) {
  const float* pred_orig = (const float*)d_in[0];   // [B,TV] fp32
  const float* pred_int  = (const float*)d_in[1];   // [K,B,TV] fp32
  const int*   idx       = (const int*)d_in[2];     // [K] int32
  const int*   gt        = (const int*)d_in[3];     // [B,TV,TS] int32
  const int*   mv        = (const int*)d_in[4];     // [B,TV] int32
  float* out = (float*)d_out;

  float* gsa = (float*)d_ws;
  float* gsv = gsa + KK * BB;
  float* gca = gsv + KK * BB;
  int*   len = (int*)(gca + KK * BB);

  // zero the 24.7 KB accumulator region (ws re-poisoned to 0xAA each call)
  hipMemsetAsync(d_ws, 0, (size_t)(3 * KK * BB) * sizeof(float) + BB * sizeof(int),
                 stream);
  fused_kernel<<<BB * NTILE, 256, 0, stream>>>(
      pred_orig, pred_int, idx, gt, mv, gsa, gsv, gca, len);
  fin_kernel<<<1, 256, 0, stream>>>(gsa, gsv, gca, len, out);
}

// Round 3
// 267.297 us; speedup vs baseline: 1.1335x; 1.1335x over previous
//
#include <hip/hip_runtime.h>
#include <cstdint>

// Problem constants (from reference)
#define BB 32
#define TV 8192
#define KK 64
#define TS 128
#define MARGIN_F 0.1f
#define LAMBDA_F 0.5f

#define TT 256                                 // t-tile per block (R3 geometry)
static constexpr int KSTR = BB * TV;           // pred_intervened stride per k
static constexpr int NTILE = TV / TT;          // 32 tiles per batch

// Workspace: gsa[KK*BB], gsv[KK*BB], gca[KK*BB], len[BB].
// en = (gsv-gsa)/(len-gca).
//
// R6 post-mortem of R5 (88->161us regression): VGPR=56 proved the 16-deep
// float2 batch never materialized (compiler sank loads to uses), while the
// request size halved to 512B/wave -> demand rate halved (930->527 GB/s).
// R6: back to TT=256 / float4 (1KB wave-requests, best measured), and
//  * sched_barrier(0) after each 8-load cluster pins 8KB/wave in flight
//    (check: VGPR must rise to ~100, else batching failed again);
//  * tile = ((bid&31)+b)&31 spreads a CU's stride-256 block set across
//    tiles (R3 gave every CU the SAME tile index -> 1.33x makespan);
//  * 3KB LDS epilogue (butterfly + lane0 atomics) instead of 36KB slabs.
__global__ __launch_bounds__(256, 4) void fused_kernel(
    const float* __restrict__ po, const float* __restrict__ pi,
    const int* __restrict__ idx, const int* __restrict__ gt,
    const int* __restrict__ mv,
    float* __restrict__ gsa, float* __restrict__ gsv,
    float* __restrict__ gca, int* __restrict__ len) {
  const int tid = threadIdx.x;
  const int lane = tid & 63;
  const int w = tid >> 6;

  const int bid = blockIdx.x;
  const int b = bid >> 5;                      // 0..31
  const int tile = ((bid & 31) + b) & 31;      // bijective per b; spreads tiles
  const int t0 = tile * TT;                    // across each CU's block set

  __shared__ unsigned long long planes[4][65]; // [row-group][k], +1 pad
  __shared__ unsigned long long sVg[4];        // valid bits per 64-row group
  __shared__ float so[TT];                     // sigmoid(pred_orig) tile

  // ---- Phase A ----  wave w owns rows [t0+64w, t0+64w+64)
  const int r0 = b * TV + t0 + w * 64;
  const unsigned long long V = __ballot(mv[r0 + lane] != 0);
  if (lane == 0) {
    sVg[w] = V;
    if (V) atomicAdd(&len[b], __popcll(V));
  }
  so[tid] = __fdividef(1.f, 1.f + __expf(-po[b * TV + t0 + tid]));

  const int c = idx[lane];                     // lane extracts column for k=lane
  const int csel = c & 3, csh = c >> 2;
  unsigned long long plane = 0ull;
  if (V != 0ull) {
    const int4* rowp = (const int4*)(gt + (size_t)r0 * TS);
#pragma unroll
    for (int batch = 0; batch < 4; ++batch) {
      int4 v[8];                               // 8 x 1KB wave-loads in flight
#pragma unroll
      for (int i = 0; i < 8; ++i) v[i] = rowp[(batch * 8 + i) * 64 + lane];
      __builtin_amdgcn_sched_barrier(0);       // pin: no sinking loads to uses
#pragma unroll
      for (int i = 0; i < 8; ++i) {
        const int ch = batch * 8 + i;          // covers rows 2ch, 2ch+1
        const unsigned long long b0 = __ballot(v[i].x > 0);
        const unsigned long long b1 = __ballot(v[i].y > 0);
        const unsigned long long b2 = __ballot(v[i].z > 0);
        const unsigned long long b3 = __ballot(v[i].w > 0);
        const unsigned long long sel =
            (csel == 0) ? b0 : (csel == 1) ? b1 : (csel == 2) ? b2 : b3;
        plane |= ((sel >> csh) & 1ull) << (2 * ch);
        plane |= ((sel >> (32 + csh)) & 1ull) << (2 * ch + 1);
      }
    }
    plane &= V;                                // aligned requires valid
  }
  planes[w][lane] = plane;
  __syncthreads();

  // fully-invalid tile: nothing to add
  if ((sVg[0] | sVg[1] | sVg[2] | sVg[3]) == 0ull) return;

  // ---- Phase B ----  lane handles t_local = 4*lane .. 4*lane+3
  const int g = lane >> 4;                     // (lane*4)>>6
  const int sh4 = (lane & 15) * 4;             // (lane*4)&63
  const unsigned vb4 = (unsigned)((sVg[g] >> sh4) & 15ull);
  const float4 so4 = *(const float4*)&so[lane * 4];
  const float* pib = pi + (size_t)b * TV + t0 + lane * 4;
  const int kbase = w * 16;                    // this wave's exclusive k range

  float sa[16], sv[16];
  int cn[16];

#pragma unroll
  for (int batch = 0; batch < 2; ++batch) {
    float4 x[8];
#pragma unroll
    for (int i = 0; i < 8; ++i) x[i] = make_float4(0.f, 0.f, 0.f, 0.f);
    if (vb4) {                                 // exec-masked 8-load cluster
#pragma unroll
      for (int i = 0; i < 8; ++i)
        x[i] = *(const float4*)(pib + (size_t)(kbase + batch * 8 + i) * KSTR);
    }
    __builtin_amdgcn_sched_barrier(0);         // pin: keep 8KB/wave in flight
#pragma unroll
    for (int i = 0; i < 8; ++i) {
      const int kk = batch * 8 + i;
      const int k = kbase + kk;
      const unsigned ab4 = (unsigned)((planes[g][k] >> sh4) & 15ull);
      const float e0 = fabsf(so4.x - __fdividef(1.f, 1.f + __expf(-x[i].x)));
      const float e1 = fabsf(so4.y - __fdividef(1.f, 1.f + __expf(-x[i].y)));
      const float e2 = fabsf(so4.z - __fdividef(1.f, 1.f + __expf(-x[i].z)));
      const float e3 = fabsf(so4.w - __fdividef(1.f, 1.f + __expf(-x[i].w)));
      float a = 0.f, vv = 0.f;
      if (ab4 & 1u) a += e0;
      if (vb4 & 1u) vv += e0;
      if (ab4 & 2u) a += e1;
      if (vb4 & 2u) vv += e1;
      if (ab4 & 4u) a += e2;
      if (vb4 & 4u) vv += e2;
      if (ab4 & 8u) a += e3;
      if (vb4 & 8u) vv += e3;
      sa[kk] = a;
      sv[kk] = vv;
      cn[kk] = __popc(ab4);                    // aligned count, this lane's 4 rows
    }
  }

  // ---- Epilogue: per-k 64-lane butterfly; one wave owns each k ----
#pragma unroll
  for (int kk = 0; kk < 16; ++kk) {
    float A = sa[kk], Vv = sv[kk];
    int C = cn[kk];
#pragma unroll
    for (int off = 32; off; off >>= 1) {
      A += __shfl_xor(A, off);
      Vv += __shfl_xor(Vv, off);
      C += __shfl_xor(C, off);
    }
    if (lane == 0) {
      const int k = kbase + kk;
      if (A != 0.f) atomicAdd(&gsa[k * BB + b], A);
      if (Vv != 0.f) atomicAdd(&gsv[k * BB + b], Vv);
      if (C) atomicAdd(&gca[k * BB + b], (float)C);
    }
  }
}

// ---------------------------------------------------------------------------
// Finalize: 1 block over the 2048 (k,b) pairs (logic verified in R2/R3).
// ---------------------------------------------------------------------------
__global__ __launch_bounds__(256) void fin_kernel(
    const float* __restrict__ gsa, const float* __restrict__ gsv,
    const float* __restrict__ gca, const int* __restrict__ len,
    float* __restrict__ out) {
  float s = 0.f;
  for (int i = threadIdx.x; i < KK * BB; i += 256) {
    const int b = i & (BB - 1);
    const float ca = gca[i];
    const float cn = (float)len[b] - ca;
    if (ca > 0.f && cn > 0.f) {
      const float sa = gsa[i];
      const float sv = gsv[i];
      const float d = MARGIN_F - (sa / ca - (sv - sa) / cn);
      s += d > 0.f ? d : 0.f;
    }
  }
#pragma unroll
  for (int off = 32; off > 0; off >>= 1) s += __shfl_down(s, off);
  __shared__ float ws4[4];
  if ((threadIdx.x & 63) == 0) ws4[threadIdx.x >> 6] = s;
  __syncthreads();
  if (threadIdx.x == 0) {
    const float S = ws4[0] + ws4[1] + ws4[2] + ws4[3];
    const float ac = S * (1.0f / (float)(KK * BB));
    out[0] = ac;
    out[1] = ac * LAMBDA_F;
  }
}

extern "C" void kernel_launch(void* const* d_in, const int* in_sizes, int n_in,
                              void* d_out, int out_size, void* d_ws, size_t ws_size,
                              hipStream_t stream) {
  const float* pred_orig = (const float*)d_in[0];   // [B,TV] fp32
  const float* pred_int  = (const float*)d_in[1];   // [K,B,TV] fp32
  const int*   idx       = (const int*)d_in[2];     // [K] int32
  const int*   gt        = (const int*)d_in[3];     // [B,TV,TS] int32
  const int*   mv        = (const int*)d_in[4];     // [B,TV] int32
  float* out = (float*)d_out;

  float* gsa = (float*)d_ws;
  float* gsv = gsa + KK * BB;
  float* gca = gsv + KK * BB;
  int*   len = (int*)(gca + KK * BB);

  // zero the 24.7 KB accumulator region (ws re-poisoned to 0xAA each call)
  hipMemsetAsync(d_ws, 0, (size_t)(3 * KK * BB) * sizeof(float) + BB * sizeof(int),
                 stream);
  fused_kernel<<<BB * NTILE, 256, 0, stream>>>(
      pred_orig, pred_int, idx, gt, mv, gsa, gsv, gca, len);
  fin_kernel<<<1, 256, 0, stream>>>(gsa, gsv, gca, len, out);
}